// Round 11
// baseline (1872.420 us; speedup 1.0000x reference)
//
#include <hip/hip_runtime.h>
#include <stdint.h>

#define Bz 256
#define Tz 128
#define DWz 768
#define DHz 768
#define G4z 3072
#define NBLK 96
#define NGRID 256

typedef __attribute__((ext_vector_type(8))) short short8;
typedef __attribute__((ext_vector_type(4))) float f32x4;
typedef __attribute__((ext_vector_type(4))) int i32x4;

__device__ __forceinline__ unsigned short f2bf(float x) {
    union { float f; unsigned int u; } v; v.f = x;
    unsigned int u = v.u;
    return (unsigned short)((u + 0x7fffu + ((u >> 16) & 1u)) >> 16);
}
__device__ __forceinline__ float bf2f(unsigned short h) {
    union { unsigned int u; float f; } v; v.u = ((unsigned int)h) << 16;
    return v.f;
}
// fast transcendentals: v_exp_f32 + v_rcp_f32 (1-ulp class, fine vs bf16 floor)
__device__ __forceinline__ float fsigm(float x) {
    return __builtin_amdgcn_rcpf(1.0f + __builtin_amdgcn_exp2f(x * -1.4426950408889634f));
}
__device__ __forceinline__ float ftanh(float x) {
    x = fminf(fmaxf(x, -15.0f), 15.0f);           // keep e finite: no inf -> NaN
    float e = __builtin_amdgcn_exp2f(x * -2.8853900817779268f);
    return (1.0f - e) * __builtin_amdgcn_rcpf(1.0f + e);
}

// ---------- all weight pre-swizzles in ONE launch (block-range dispatch) ----------
__global__ __launch_bounds__(256) void k_prep_all(const float* __restrict__ W_ih,
                                                  const float* __restrict__ Wh,
                                                  const float* __restrict__ Wp,
                                                  const float* __restrict__ Wx,
                                                  unsigned short* __restrict__ WihbP,
                                                  unsigned short* __restrict__ Wih2P,
                                                  unsigned short* __restrict__ WhbP,
                                                  unsigned short* __restrict__ WpxP) {
    __shared__ float sT[32][132];
    int bid = blockIdx.x;
    const float* W; unsigned short* out; int NT, rb;
    if (bid < 576)       { W = W_ih;                        out = WihbP; NT = 24; rb = bid; }
    else if (bid < 1152) { W = W_ih + (size_t)DWz * G4z;    out = Wih2P; NT = 24; rb = bid - 576; }
    else if (bid < 1296) { W = Wh;                          out = WhbP;  NT = 6;  rb = bid - 1152; }
    else if (bid < 1440) { W = Wp;                          out = WpxP;  NT = 6;  rb = bid - 1296; }
    else                 { W = Wx; out = WpxP + (size_t)144 * 512 * 8;   NT = 6;  rb = bid - 1440; }
    int kt = rb / NT, nt = rb - kt * NT;
    int tid = threadIdx.x;
    int ldn = NT * 128;
    {
        int r = tid >> 3;
        int cb = (tid & 7) * 16;
        const float* src = W + (long)(kt * 32 + r) * ldn + nt * 128 + cb;
#pragma unroll
        for (int u = 0; u < 4; ++u) {
            float4 v = ((const float4*)src)[u];
            sT[r][cb + u * 4 + 0] = v.x; sT[r][cb + u * 4 + 1] = v.y;
            sT[r][cb + u * 4 + 2] = v.z; sT[r][cb + u * 4 + 3] = v.w;
        }
    }
    __syncthreads();
#pragma unroll
    for (int it = 0; it < 2; ++it) {
        int s = tid + it * 256;
        int n = s >> 2, kq = s & 3;
        alignas(16) unsigned short o[8];
#pragma unroll
        for (int e = 0; e < 8; ++e) o[e] = f2bf(sT[kq * 8 + e][n]);
        *(int4*)(out + ((long)rb * 512 + s) * 8) = *(const int4*)o;
    }
}

// ---------- Whh -> pre-swizzled bf16 blobs (coalesced reads via LDS transpose) ----
__global__ __launch_bounds__(256) void k_prep_whh(const float* __restrict__ Whh,
                                                  unsigned short* __restrict__ WhhP) {
    __shared__ float sT[32][65];
    int bid = blockIdx.x;            // [0, 1152)
    int dblk = bid / 24;
    int k0c = bid - dblk * 24;
    int tid = threadIdx.x;
    {
        int kk = tid >> 3;
        int seg = tid & 7;
        const float* src = Whh + (long)(k0c * 32 + kk) * G4z
                         + (seg >> 1) * 768 + dblk * 16 + (seg & 1) * 8;
        float4 v0 = *(const float4*)src;
        float4 v1 = *(const float4*)(src + 4);
        int cl = seg * 8;
        sT[kk][cl + 0] = v0.x; sT[kk][cl + 1] = v0.y; sT[kk][cl + 2] = v0.z; sT[kk][cl + 3] = v0.w;
        sT[kk][cl + 4] = v1.x; sT[kk][cl + 5] = v1.y; sT[kk][cl + 6] = v1.z; sT[kk][cl + 7] = v1.w;
    }
    __syncthreads();
    {
        int nl = tid >> 2, cc = tid & 3;
        int q8 = cc ^ ((nl >> 1) & 3);
        int clv = (nl >> 4) * 16 + (nl & 15);
        alignas(16) unsigned short o[8];
#pragma unroll
        for (int e = 0; e < 8; ++e) o[e] = f2bf(sT[q8 * 8 + e][clv]);
        *(int4*)(WhhP + (long)(dblk * 6144 + k0c * 256 + tid) * 8) = *(const int4*)o;
    }
}

// ---------- constg GEMM (fallback path only) ----------
__global__ __launch_bounds__(256) void k_gemm_cg(const int* __restrict__ target,
                                                 const float* __restrict__ temb,
                                                 const unsigned short* __restrict__ WbP,
                                                 const float* __restrict__ bias,
                                                 float* __restrict__ C) {
    __shared__ unsigned short sA[128 * 40];
    __shared__ unsigned short sB[128 * 40];
    int tid = threadIdx.x;
    int n0 = blockIdx.x * 128;
    int m0 = blockIdx.y * 128;
    int wid = tid >> 6, lane = tid & 63, l15 = lane & 15, q = lane >> 4;
    int wm = wid >> 1, wn = wid & 1;
    int arow = tid >> 1;
    int kp = (tid & 1) * 16;
    long gbase = (long)target[m0 + arow] * DWz;
    int s0 = tid, s1 = tid + 256;
    int bd0 = (s0 >> 2) * 40 + (((s0 & 3) ^ (((s0 >> 2) >> 3) & 3)) << 3);
    int bd1 = (s1 >> 2) * 40 + (((s1 & 3) ^ (((s1 >> 2) >> 3) & 3)) << 3);

    f32x4 acc[4][4];
    f32x4 zz = {0.f, 0.f, 0.f, 0.f};
#pragma unroll
    for (int i = 0; i < 4; ++i)
#pragma unroll
        for (int j = 0; j < 4; ++j) acc[i][j] = zz;

    for (int k0 = 0; k0 < DWz; k0 += 32) {
        {
            const float* src = temb + gbase + k0 + kp;
            alignas(16) unsigned short tmp[16];
#pragma unroll
            for (int it = 0; it < 4; ++it) {
                float4 v = ((const float4*)src)[it];
                tmp[it * 4 + 0] = f2bf(v.x); tmp[it * 4 + 1] = f2bf(v.y);
                tmp[it * 4 + 2] = f2bf(v.z); tmp[it * 4 + 3] = f2bf(v.w);
            }
            *(int4*)(sA + arow * 40 + kp) = *(const int4*)tmp;
            *(int4*)(sA + arow * 40 + kp + 8) = *(const int4*)(tmp + 8);
        }
        {
            const int4* wsrc = (const int4*)WbP
                + ((long)((k0 >> 5) * 24 + (n0 >> 7))) * 512 + tid;
            int4 v0 = wsrc[0];
            int4 v1 = wsrc[256];
            *(int4*)(sB + bd0) = v0;
            *(int4*)(sB + bd1) = v1;
        }
        __syncthreads();
        short8 af[4], bfr[4];
#pragma unroll
        for (int i = 0; i < 4; ++i)
            af[i] = *(const short8*)(sA + (wm * 64 + i * 16 + l15) * 40 + q * 8);
#pragma unroll
        for (int j = 0; j < 4; ++j) {
            int n = wn * 64 + j * 16 + l15;
            bfr[j] = *(const short8*)(sB + n * 40 + ((q ^ ((n >> 3) & 3)) << 3));
        }
#pragma unroll
        for (int i = 0; i < 4; ++i)
#pragma unroll
            for (int j = 0; j < 4; ++j)
                acc[i][j] = __builtin_amdgcn_mfma_f32_16x16x32_bf16(af[i], bfr[j], acc[i][j], 0, 0, 0);
        __syncthreads();
    }
#pragma unroll
    for (int i = 0; i < 4; ++i)
#pragma unroll
        for (int j = 0; j < 4; ++j) {
            int col = n0 + wn * 64 + j * 16 + l15;
            float bv = bias[col];
#pragma unroll
            for (int r = 0; r < 4; ++r) {
                int row = m0 + wm * 64 + i * 16 + q * 4 + r;
                C[(long)row * G4z + col] = acc[i][j][r] + bv;
            }
        }
}

// ---------- standalone xW GEMM (fallback path only) ----------
__global__ __launch_bounds__(256) void k_gemm_x(const float* __restrict__ emb,
                                                const int* __restrict__ sent,
                                                const unsigned short* __restrict__ WbP,
                                                unsigned short* __restrict__ xW) {
    __shared__ unsigned short sA[128 * 40];
    __shared__ unsigned short sB[128 * 40];
    int tid = threadIdx.x;
    int n0 = blockIdx.x * 128;
    int m0 = blockIdx.y * 128;
    int wid = tid >> 6, lane = tid & 63, l15 = lane & 15, q = lane >> 4;
    int wm = wid >> 1, wn = wid & 1;
    int arow = tid >> 1;
    int kp = (tid & 1) * 16;
    int m = m0 + arow;
    int tt = m >> 8;
    int bb = m & 255;
    long gbase = (long)sent[bb * Tz + tt] * DWz;
    int s0 = tid, s1 = tid + 256;
    int bd0 = (s0 >> 2) * 40 + (((s0 & 3) ^ (((s0 >> 2) >> 3) & 3)) << 3);
    int bd1 = (s1 >> 2) * 40 + (((s1 & 3) ^ (((s1 >> 2) >> 3) & 3)) << 3);

    f32x4 acc[4][4];
    f32x4 zz = {0.f, 0.f, 0.f, 0.f};
#pragma unroll
    for (int i = 0; i < 4; ++i)
#pragma unroll
        for (int j = 0; j < 4; ++j) acc[i][j] = zz;

    for (int k0 = 0; k0 < DWz; k0 += 32) {
        {
            const float* src = emb + gbase + k0 + kp;
            alignas(16) unsigned short tmp[16];
#pragma unroll
            for (int it = 0; it < 4; ++it) {
                float4 v = ((const float4*)src)[it];
                tmp[it * 4 + 0] = f2bf(v.x); tmp[it * 4 + 1] = f2bf(v.y);
                tmp[it * 4 + 2] = f2bf(v.z); tmp[it * 4 + 3] = f2bf(v.w);
            }
            *(int4*)(sA + arow * 40 + kp) = *(const int4*)tmp;
            *(int4*)(sA + arow * 40 + kp + 8) = *(const int4*)(tmp + 8);
        }
        {
            const int4* wsrc = (const int4*)WbP
                + ((long)((k0 >> 5) * 24 + (n0 >> 7))) * 512 + tid;
            int4 v0 = wsrc[0];
            int4 v1 = wsrc[256];
            *(int4*)(sB + bd0) = v0;
            *(int4*)(sB + bd1) = v1;
        }
        __syncthreads();
        short8 af[4], bfr[4];
#pragma unroll
        for (int i = 0; i < 4; ++i)
            af[i] = *(const short8*)(sA + (wm * 64 + i * 16 + l15) * 40 + q * 8);
#pragma unroll
        for (int j = 0; j < 4; ++j) {
            int n = wn * 64 + j * 16 + l15;
            bfr[j] = *(const short8*)(sB + n * 40 + ((q ^ ((n >> 3) & 3)) << 3));
        }
#pragma unroll
        for (int i = 0; i < 4; ++i)
#pragma unroll
            for (int j = 0; j < 4; ++j)
                acc[i][j] = __builtin_amdgcn_mfma_f32_16x16x32_bf16(af[i], bfr[j], acc[i][j], 0, 0, 0);
        __syncthreads();
    }
#pragma unroll
    for (int j = 0; j < 4; ++j) {
        int n = n0 + wn * 64 + j * 16 + l15;
        int gt = n / 768;
        int dblk = (n - gt * 768) >> 4;
#pragma unroll
        for (int ip = 0; ip < 2; ++ip) {
            int row = m0 + wm * 64 + ip * 32;
            int t = row >> 8;
            int bq = (row & 255) + q * 4;
            int blk = dblk * 2 + (bq >> 7);
            int tidd = ((bq & 127) >> 5) * 64 + q * 16 + l15;
            alignas(16) unsigned short o[8];
#pragma unroll
            for (int r = 0; r < 4; ++r) {
                o[r]     = f2bf(acc[ip * 2][j][r]);
                o[4 + r] = f2bf(acc[ip * 2 + 1][j][r]);
            }
            *(int4*)(xW + (((long)t * 96 + blk) * 4 + gt) * 2048 + (long)tidd * 8) = *(const int4*)o;
        }
    }
}

// ---------- MEGAKERNEL ----------
// Blocks 0..95: LSTM (round-3 wave-dataflow, unchanged) then epilogue tasks.
// Blocks 96..255: cg tiles -> xW tiles -> score tiles -> epilogue tasks.
// All cross-phase data flows via agent write-through + L3-resident counters:
//   ctr[0]=cg tiles done(48), ctr[32]=score tiles(1536), ctr[64]=attn rows(256),
//   ctr[96]=hstar tiles(12). Epilogue task space: 0..255 attn, 256..267 hstar,
//   268..523 logits. Gates are acyclic -> no deadlock.
#define UNPACK(PF, G)                                                        \
    {                                                                        \
        const unsigned short* ch_ = (const unsigned short*)&(PF);            \
        _Pragma("unroll")                                                    \
        for (int i_ = 0; i_ < 2; ++i_)                                       \
            _Pragma("unroll")                                                \
            for (int r_ = 0; r_ < 4; ++r_)                                   \
                xg[i_][G][r_] = bf2f(ch_[i_ * 4 + r_]) + xgc[i_][G][r_];     \
    }

__global__ __launch_bounds__(256, 1) void k_lstm_all(int t0, int t1,
        unsigned short* __restrict__ xW, float* __restrict__ constg,
        const unsigned short* __restrict__ WhhP, unsigned short* __restrict__ Hbf,
        float* __restrict__ cbuf, const int* __restrict__ lens,
        unsigned* __restrict__ bar, unsigned* __restrict__ xwcnt, int fused,
        const float* __restrict__ emb, const int* __restrict__ sent,
        const unsigned short* __restrict__ WihbP, int nprod,
        const unsigned short* __restrict__ WhbP, const float* __restrict__ wv,
        float* __restrict__ scores,
        const int* __restrict__ target, const float* __restrict__ temb,
        const unsigned short* __restrict__ Wih2P, const float* __restrict__ b_lstm,
        float* __restrict__ rbuf, const unsigned short* __restrict__ WpxP,
        float* __restrict__ hst, const float* __restrict__ W_lin,
        const float* __restrict__ b_lin, float* __restrict__ out) {
    extern __shared__ unsigned short sB[];   // 96 KB dynamic
    int bid = blockIdx.x;
    int tid = threadIdx.x;
    int lane = tid & 63, wid = tid >> 6;
    int l15 = lane & 15, q = lane >> 4;
    unsigned* ctr = bar + 12288;   // 4 counter lines in bar's spare tail

    if (bid >= NBLK) {
        // ---------------- producer ----------------
        unsigned short* psA = sB;
        unsigned short* psB = sB + 5120;
        float* sred = (float*)(sB + 10240);
        int wm = wid >> 1, wn = wid & 1;
        int arow = tid >> 1;
        int kp = (tid & 1) * 16;
        int s0 = tid, s1 = tid + 256;
        int bd0 = (s0 >> 2) * 40 + (((s0 & 3) ^ (((s0 >> 2) >> 3) & 3)) << 3);
        int bd1 = (s1 >> 2) * 40 + (((s1 & 3) ^ (((s1 >> 2) >> 3) & 3)) << 3);

        // ---- phase 0: constg tiles (48) ----
        for (int cg = bid - NBLK; cg < 48; cg += nprod) {
            int my = cg / 24, nx = cg - my * 24;
            int m0 = my * 128, n0 = nx * 128;
            long gbase = (long)target[m0 + arow] * DWz;
            f32x4 acc[4][4];
            f32x4 zz = {0.f, 0.f, 0.f, 0.f};
#pragma unroll
            for (int i = 0; i < 4; ++i)
#pragma unroll
                for (int j = 0; j < 4; ++j) acc[i][j] = zz;
            for (int k0 = 0; k0 < DWz; k0 += 32) {
                {
                    const float* src = temb + gbase + k0 + kp;
                    alignas(16) unsigned short tmp[16];
#pragma unroll
                    for (int it = 0; it < 4; ++it) {
                        float4 v = ((const float4*)src)[it];
                        tmp[it * 4 + 0] = f2bf(v.x); tmp[it * 4 + 1] = f2bf(v.y);
                        tmp[it * 4 + 2] = f2bf(v.z); tmp[it * 4 + 3] = f2bf(v.w);
                    }
                    *(int4*)(psA + arow * 40 + kp) = *(const int4*)tmp;
                    *(int4*)(psA + arow * 40 + kp + 8) = *(const int4*)(tmp + 8);
                }
                {
                    const int4* wsrc = (const int4*)Wih2P
                        + ((long)((k0 >> 5) * 24 + (n0 >> 7))) * 512 + tid;
                    int4 v0 = wsrc[0];
                    int4 v1 = wsrc[256];
                    *(int4*)(psB + bd0) = v0;
                    *(int4*)(psB + bd1) = v1;
                }
                __syncthreads();
                short8 af[4], bfr[4];
#pragma unroll
                for (int i = 0; i < 4; ++i)
                    af[i] = *(const short8*)(psA + (wm * 64 + i * 16 + l15) * 40 + q * 8);
#pragma unroll
                for (int j = 0; j < 4; ++j) {
                    int n = wn * 64 + j * 16 + l15;
                    bfr[j] = *(const short8*)(psB + n * 40 + ((q ^ ((n >> 3) & 3)) << 3));
                }
#pragma unroll
                for (int i = 0; i < 4; ++i)
#pragma unroll
                    for (int j = 0; j < 4; ++j)
                        acc[i][j] = __builtin_amdgcn_mfma_f32_16x16x32_bf16(af[i], bfr[j], acc[i][j], 0, 0, 0);
                __syncthreads();
            }
#pragma unroll
            for (int i = 0; i < 4; ++i)
#pragma unroll
                for (int j = 0; j < 4; ++j) {
                    int col = n0 + wn * 64 + j * 16 + l15;
                    float bv = b_lstm[col];
#pragma unroll
                    for (int r = 0; r < 4; ++r) {
                        int row = m0 + wm * 64 + i * 16 + q * 4 + r;
                        __hip_atomic_store(&constg[(long)row * G4z + col],
                                           acc[i][j][r] + bv,
                                           __ATOMIC_RELAXED, __HIP_MEMORY_SCOPE_AGENT);
                    }
                }
            asm volatile("s_waitcnt vmcnt(0)" ::: "memory");
            __syncthreads();
            if (tid == 0)
                (void)__hip_atomic_fetch_add(ctr, 1u, __ATOMIC_RELAXED,
                                             __HIP_MEMORY_SCOPE_AGENT);
        }

        // ---- phase 1: xW tiles (6144) ----
        for (int g = bid - NBLK; g < 6144; g += nprod) {
            int my = g / 24, nx = g - (g / 24) * 24;
            int m0 = my * 128, n0 = nx * 128;
            int m = m0 + arow;
            int tt = m >> 8, bb2 = m & 255;
            long gbase = (long)sent[bb2 * Tz + tt] * DWz;

            f32x4 acc[4][4];
            f32x4 zz = {0.f, 0.f, 0.f, 0.f};
#pragma unroll
            for (int i = 0; i < 4; ++i)
#pragma unroll
                for (int j = 0; j < 4; ++j) acc[i][j] = zz;

            for (int k0 = 0; k0 < DWz; k0 += 32) {
                {
                    const float* src = emb + gbase + k0 + kp;
                    alignas(16) unsigned short tmp[16];
#pragma unroll
                    for (int it = 0; it < 4; ++it) {
                        float4 v = ((const float4*)src)[it];
                        tmp[it * 4 + 0] = f2bf(v.x); tmp[it * 4 + 1] = f2bf(v.y);
                        tmp[it * 4 + 2] = f2bf(v.z); tmp[it * 4 + 3] = f2bf(v.w);
                    }
                    *(int4*)(psA + arow * 40 + kp) = *(const int4*)tmp;
                    *(int4*)(psA + arow * 40 + kp + 8) = *(const int4*)(tmp + 8);
                }
                {
                    const int4* wsrc = (const int4*)WihbP
                        + ((long)((k0 >> 5) * 24 + (n0 >> 7))) * 512 + tid;
                    int4 v0 = wsrc[0];
                    int4 v1 = wsrc[256];
                    *(int4*)(psB + bd0) = v0;
                    *(int4*)(psB + bd1) = v1;
                }
                __syncthreads();
                short8 af[4], bfr[4];
#pragma unroll
                for (int i = 0; i < 4; ++i)
                    af[i] = *(const short8*)(psA + (wm * 64 + i * 16 + l15) * 40 + q * 8);
#pragma unroll
                for (int j = 0; j < 4; ++j) {
                    int n = wn * 64 + j * 16 + l15;
                    bfr[j] = *(const short8*)(psB + n * 40 + ((q ^ ((n >> 3) & 3)) << 3));
                }
#pragma unroll
                for (int i = 0; i < 4; ++i)
#pragma unroll
                    for (int j = 0; j < 4; ++j)
                        acc[i][j] = __builtin_amdgcn_mfma_f32_16x16x32_bf16(af[i], bfr[j], acc[i][j], 0, 0, 0);
                __syncthreads();
            }
#pragma unroll
            for (int j = 0; j < 4; ++j) {
                int n = n0 + wn * 64 + j * 16 + l15;
                int gt = n / 768;
                int dblk2 = (n - gt * 768) >> 4;
#pragma unroll
                for (int ip = 0; ip < 2; ++ip) {
                    int row = m0 + wm * 64 + ip * 32;
                    int t = row >> 8;
                    int bq = (row & 255) + q * 4;
                    int blk = dblk2 * 2 + (bq >> 7);
                    int tidd = ((bq & 127) >> 5) * 64 + q * 16 + l15;
                    alignas(16) unsigned short o[8];
#pragma unroll
                    for (int r = 0; r < 4; ++r) {
                        o[r]     = f2bf(acc[ip * 2][j][r]);
                        o[4 + r] = f2bf(acc[ip * 2 + 1][j][r]);
                    }
                    unsigned long long* dst = (unsigned long long*)
                        (xW + (((long)t * 96 + blk) * 4 + gt) * 2048 + (long)tidd * 8);
                    const unsigned long long* po = (const unsigned long long*)o;
                    __hip_atomic_store(dst, po[0], __ATOMIC_RELAXED, __HIP_MEMORY_SCOPE_AGENT);
                    __hip_atomic_store(dst + 1, po[1], __ATOMIC_RELAXED, __HIP_MEMORY_SCOPE_AGENT);
                }
            }
            asm volatile("s_waitcnt vmcnt(0)" ::: "memory");
            __syncthreads();
            if (tid == 0)
                (void)__hip_atomic_fetch_add(&xwcnt[(my >> 1) * 32], 1u,
                                             __ATOMIC_RELAXED, __HIP_MEMORY_SCOPE_AGENT);
        }

        // ---- phase 2: score tiles (1536 = 128 t x 2 m x 6 n) ----
        for (int s2 = bid - NBLK; s2 < 1536; s2 += nprod) {
            int t = s2 / 12;
            int rr = s2 - t * 12;
            int mt = rr / 6, nt2 = rr - (rr / 6) * 6;
            int m0 = mt * 128, n0 = nt2 * 128;
            unsigned tgt = (unsigned)(t + 1);
            {
                const unsigned* fp2 = bar + (((mt * 4 + wid) * 48) + lane) * 32;
                while (true) {
                    unsigned v = (lane < 48)
                        ? __hip_atomic_load(fp2, __ATOMIC_RELAXED, __HIP_MEMORY_SCOPE_AGENT)
                        : tgt;
                    if (__all(v >= tgt)) break;
                    __builtin_amdgcn_s_sleep(8);
                }
            }
            __syncthreads();

            f32x4 acc[4][4];
            f32x4 zz = {0.f, 0.f, 0.f, 0.f};
#pragma unroll
            for (int i = 0; i < 4; ++i)
#pragma unroll
                for (int j = 0; j < 4; ++j) acc[i][j] = zz;

            for (int k0 = 0; k0 < DHz; k0 += 32) {
                {
                    const unsigned short* asrc = Hbf
                        + ((long)(m0 + arow) * Tz + t) * DHz + k0 + kp;
                    *(int4*)(psA + arow * 40 + kp) = *(const int4*)asrc;
                    *(int4*)(psA + arow * 40 + kp + 8) = *(const int4*)(asrc + 8);
                }
                {
                    const int4* wsrc = (const int4*)WhbP
                        + ((long)((k0 >> 5) * 6 + nt2)) * 512 + tid;
                    int4 v0 = wsrc[0];
                    int4 v1 = wsrc[256];
                    *(int4*)(psB + bd0) = v0;
                    *(int4*)(psB + bd1) = v1;
                }
                __syncthreads();
                short8 af[4], bfr[4];
#pragma unroll
                for (int i = 0; i < 4; ++i)
                    af[i] = *(const short8*)(psA + (wm * 64 + i * 16 + l15) * 40 + q * 8);
#pragma unroll
                for (int j = 0; j < 4; ++j) {
                    int n = wn * 64 + j * 16 + l15;
                    bfr[j] = *(const short8*)(psB + n * 40 + ((q ^ ((n >> 3) & 3)) << 3));
                }
#pragma unroll
                for (int i = 0; i < 4; ++i)
#pragma unroll
                    for (int j = 0; j < 4; ++j)
                        acc[i][j] = __builtin_amdgcn_mfma_f32_16x16x32_bf16(af[i], bfr[j], acc[i][j], 0, 0, 0);
                __syncthreads();
            }
            if (tid < 128) sred[tid] = 0.f;
            __syncthreads();
#pragma unroll
            for (int i = 0; i < 4; ++i)
#pragma unroll
                for (int r = 0; r < 4; ++r) {
                    float sv = 0.f;
#pragma unroll
                    for (int j = 0; j < 4; ++j) {
                        int n = n0 + wn * 64 + j * 16 + l15;
                        sv += ftanh(acc[i][j][r]) * wv[n];
                    }
#pragma unroll
                    for (int o = 1; o < 16; o <<= 1) sv += __shfl_xor(sv, o, 64);
                    if (l15 == 0) atomicAdd(&sred[wm * 64 + i * 16 + q * 4 + r], sv);
                }
            __syncthreads();
            if (tid < 128)
                atomicAdd(&scores[(long)(m0 + tid) * Tz + t], sred[tid]);
            asm volatile("s_waitcnt vmcnt(0)" ::: "memory");
            __syncthreads();
            if (tid == 0)
                (void)__hip_atomic_fetch_add(ctr + 32, 1u, __ATOMIC_RELAXED,
                                             __HIP_MEMORY_SCOPE_AGENT);
        }
    } else {
        // ---------------- consumer: LSTM ----------------
        int bm = bid & 1;
        int dblk = bid >> 1;
        int d0 = dblk * 16;
        int d = d0 + l15;
        unsigned* flg = bar + ((bm * 4 + wid) * 48) * 32;

        {   // stage pre-swizzled Whh once
            const int4* src = (const int4*)WhhP + (long)dblk * 6144;
            for (int s = tid; s < 6144; s += 256) ((int4*)sB)[s] = src[s];
        }

        int brow[8];
        int lenr[8];
        float c[8], h[8];
#pragma unroll
        for (int i = 0; i < 2; ++i)
#pragma unroll
            for (int r = 0; r < 4; ++r) {
                int ir = i * 4 + r;
                int b = bm * 128 + wid * 32 + i * 16 + q * 4 + r;
                brow[ir] = b;
                lenr[ir] = lens[b];
                if (t0 > 0) {
                    c[ir] = cbuf[(long)b * DHz + d];
                    h[ir] = bf2f(Hbf[((long)b * Tz + (t0 - 1)) * DHz + d]);
                } else { c[ir] = 0.f; h[ir] = 0.f; }
            }

        int bbase[4];
#pragma unroll
        for (int j = 0; j < 4; ++j) {
            int nl = j * 16 + l15;
            bbase[j] = nl * 32 + ((q ^ ((nl >> 1) & 3)) << 3);
        }
        // gate constg (produced in-kernel when fused)
        if (fused && tid == 0)
            while (__hip_atomic_load(ctr, __ATOMIC_RELAXED, __HIP_MEMORY_SCOPE_AGENT) < 48u)
                __builtin_amdgcn_s_sleep(1);
        __syncthreads();

        float xgc[2][4][4];
#pragma unroll
        for (int i = 0; i < 2; ++i)
#pragma unroll
            for (int r = 0; r < 4; ++r) {
                long cbase = (long)brow[i * 4 + r] * G4z + d;
#pragma unroll
                for (int j = 0; j < 4; ++j) xgc[i][j][r] = constg[cbase + j * 768];
            }

        if (fused) {
            const unsigned* xc = xwcnt + t0 * 32;
            if (lane == 0)
                while (__hip_atomic_load(xc, __ATOMIC_RELAXED, __HIP_MEMORY_SCOPE_AGENT) < 48u)
                    __builtin_amdgcn_s_sleep(1);
            asm volatile("" ::: "memory");
        }
        float xg[2][4][4];
        {
            const unsigned short* x0 = xW + ((long)t0 * 96 + bid) * 8192 + (long)tid * 8;
            int4 c0 = *(const int4*)(x0);
            int4 c1 = *(const int4*)(x0 + 2048);
            int4 c2 = *(const int4*)(x0 + 4096);
            int4 c3 = *(const int4*)(x0 + 6144);
            UNPACK(c0, 0) UNPACK(c1, 1) UNPACK(c2, 2) UNPACK(c3, 3)
        }

        i32x4 pf0, pf1, pf2, pf3;

        for (int t = t0; t < t1; ++t) {
            if (t > t0) {
                unsigned tgt = (unsigned)t;
                const unsigned* fp = flg + lane * 32;
                while (true) {
                    unsigned v = (lane < 48)
                        ? __hip_atomic_load(fp, __ATOMIC_RELAXED, __HIP_MEMORY_SCOPE_AGENT)
                        : tgt;
                    if (__all(v >= tgt)) break;
                    __builtin_amdgcn_s_sleep(1);
                }
                asm volatile("s_waitcnt vmcnt(0)" ::: "memory");
                __builtin_amdgcn_sched_barrier(0);
                UNPACK(pf0, 0) UNPACK(pf1, 1) UNPACK(pf2, 2) UNPACK(pf3, 3)
            }

            f32x4 acc[2][4];
            f32x4 zz = {0.f, 0.f, 0.f, 0.f};
#pragma unroll
            for (int i = 0; i < 2; ++i)
#pragma unroll
                for (int j = 0; j < 4; ++j) acc[i][j] = zz;

            if (t > 0) {
                const unsigned short* ap0 = Hbf + ((long)(bm * 128 + wid * 32 + l15) * Tz + (t - 1)) * DHz + q * 8;
                const unsigned short* ap1 = ap0 + (long)16 * Tz * DHz;
#pragma unroll 6
                for (int k0c = 0; k0c < 24; ++k0c) {
                    short8 a0 = *(const short8*)(ap0 + k0c * 32);
                    short8 a1 = *(const short8*)(ap1 + k0c * 32);
                    const unsigned short* bb = sB + k0c * 2048;
#pragma unroll
                    for (int j = 0; j < 4; ++j) {
                        short8 bf = *(const short8*)(bb + bbase[j]);
                        acc[0][j] = __builtin_amdgcn_mfma_f32_16x16x32_bf16(a0, bf, acc[0][j], 0, 0, 0);
                        acc[1][j] = __builtin_amdgcn_mfma_f32_16x16x32_bf16(a1, bf, acc[1][j], 0, 0, 0);
                    }
                }
            }

#pragma unroll
            for (int i = 0; i < 2; ++i)
#pragma unroll
                for (int r = 0; r < 4; ++r) {
                    int ir = i * 4 + r;
                    float gi = acc[i][0][r] + xg[i][0][r];
                    float gf = acc[i][1][r] + xg[i][1][r];
                    float gg = acc[i][2][r] + xg[i][2][r];
                    float go = acc[i][3][r] + xg[i][3][r];
                    float cn = fsigm(gf) * c[ir] + fsigm(gi) * ftanh(gg);
                    float hn = fsigm(go) * ftanh(cn);
                    bool upd = t < lenr[ir];
                    c[ir] = upd ? cn : c[ir];
                    h[ir] = upd ? hn : h[ir];
                    __hip_atomic_store(Hbf + ((long)brow[ir] * Tz + t) * DHz + d, f2bf(h[ir]),
                                       __ATOMIC_RELAXED, __HIP_MEMORY_SCOPE_AGENT);
                }

            if (t + 1 < t1) {
                if (fused) {
                    const unsigned* xc = xwcnt + (t + 1) * 32;
                    if (lane == 0)
                        while (__hip_atomic_load(xc, __ATOMIC_RELAXED, __HIP_MEMORY_SCOPE_AGENT) < 48u)
                            __builtin_amdgcn_s_sleep(1);
                    asm volatile("" ::: "memory");
                }
                const unsigned short* pp = xW + ((long)(t + 1) * 96 + bid) * 8192 + (long)tid * 8;
                asm volatile(
                    "global_load_dwordx4 %0, %4, off\n\t"
                    "global_load_dwordx4 %1, %5, off\n\t"
                    "global_load_dwordx4 %2, %6, off\n\t"
                    "global_load_dwordx4 %3, %7, off"
                    : "=&v"(pf0), "=&v"(pf1), "=&v"(pf2), "=&v"(pf3)
                    : "v"(pp), "v"(pp + 2048), "v"(pp + 4096), "v"(pp + 6144)
                    : "memory");
                asm volatile("s_waitcnt vmcnt(4)" ::: "memory");
                if (lane == 0)
                    __hip_atomic_store(flg + dblk * 32, (unsigned)(t + 1),
                                       __ATOMIC_RELAXED, __HIP_MEMORY_SCOPE_AGENT);
            }
        }
        // final-step publish (gates producer score tiles for t = t1-1)
        asm volatile("s_waitcnt vmcnt(0)" ::: "memory");
        if (lane == 0)
            __hip_atomic_store(flg + dblk * 32, (unsigned)t1,
                               __ATOMIC_RELAXED, __HIP_MEMORY_SCOPE_AGENT);
#pragma unroll
        for (int ir = 0; ir < 8; ++ir) cbuf[(long)brow[ir] * DHz + d] = c[ir];
    }

    if (!fused) return;

    // ---------------- in-kernel epilogue (all 256 blocks) ----------------
    __syncthreads();
    {
        unsigned short* eA = sB;
        unsigned short* eB = sB + 5120;
        float* esal = (float*)(sB + 10240);   // [128]
        float* erAB = esal + 128;             // [4]
        int wm = wid >> 1, wn = wid & 1;
        int arow = tid >> 1;
        int kp = (tid & 1) * 16;
        int s0 = tid, s1 = tid + 256;
        int bd0 = (s0 >> 2) * 40 + (((s0 & 3) ^ (((s0 >> 2) >> 3) & 3)) << 3);
        int bd1 = (s1 >> 2) * 40 + (((s1 & 3) ^ (((s1 >> 2) >> 3) & 3)) << 3);

        for (int task = bid; task < 524; task += NGRID) {
            if (task < 256) {
                // ---- attn row b: softmax + r ----
                int b = task;
                if (tid == 0)
                    while (__hip_atomic_load(ctr + 32, __ATOMIC_RELAXED,
                                             __HIP_MEMORY_SCOPE_AGENT) < 1536u)
                        __builtin_amdgcn_s_sleep(8);
                __syncthreads();
                float e = 0.f, mm = 0.f, sv = 0.f;
                if (tid < 128) {
                    int len = lens[b];
                    sv = (tid < len) ? scores[b * Tz + tid] : -1e9f;
                    mm = sv;
#pragma unroll
                    for (int o = 32; o; o >>= 1) mm = fmaxf(mm, __shfl_xor(mm, o, 64));
                    if ((tid & 63) == 0) erAB[tid >> 6] = mm;
                }
                __syncthreads();
                if (tid < 128) {
                    mm = fmaxf(erAB[0], erAB[1]);
                    e = expf(sv - mm);
                    float sum = e;
#pragma unroll
                    for (int o = 32; o; o >>= 1) sum += __shfl_xor(sum, o, 64);
                    if ((tid & 63) == 0) erAB[2 + (tid >> 6)] = sum;
                }
                __syncthreads();
                if (tid < 128) esal[tid] = e / (erAB[2] + erAB[3]);
                __syncthreads();
                if (tid < 96) {
                    const unsigned short* hp = Hbf + (long)b * Tz * DHz + tid * 8;
                    float acc8[8] = {};
                    for (int tt = 0; tt < Tz; ++tt) {
                        short8 v = *(const short8*)(hp + (long)tt * DHz);
                        float a = esal[tt];
                        const unsigned short* pv = (const unsigned short*)&v;
#pragma unroll
                        for (int e2 = 0; e2 < 8; ++e2) acc8[e2] += a * bf2f(pv[e2]);
                    }
                    float* rp = rbuf + (long)b * DHz + tid * 8;
#pragma unroll
                    for (int e2 = 0; e2 < 8; e2 += 2) {
                        union { float f[2]; unsigned long long u; } pk;
                        pk.f[0] = acc8[e2]; pk.f[1] = acc8[e2 + 1];
                        __hip_atomic_store((unsigned long long*)(rp + e2), pk.u,
                                           __ATOMIC_RELAXED, __HIP_MEMORY_SCOPE_AGENT);
                    }
                }
                asm volatile("s_waitcnt vmcnt(0)" ::: "memory");
                __syncthreads();
                if (tid == 0)
                    (void)__hip_atomic_fetch_add(ctr + 64, 1u, __ATOMIC_RELAXED,
                                                 __HIP_MEMORY_SCOPE_AGENT);
            } else if (task < 268) {
                // ---- hstar tile: tanh([r | H_last] @ [Wp;Wx]) ----
                int tile = task - 256;
                int mt = tile / 6, nt2 = tile - mt * 6;
                int m0 = mt * 128, n0 = nt2 * 128;
                if (tid == 0)
                    while (__hip_atomic_load(ctr + 64, __ATOMIC_RELAXED,
                                             __HIP_MEMORY_SCOPE_AGENT) < 256u)
                        __builtin_amdgcn_s_sleep(8);
                __syncthreads();
                f32x4 acc[4][4];
                f32x4 zz = {0.f, 0.f, 0.f, 0.f};
#pragma unroll
                for (int i = 0; i < 4; ++i)
#pragma unroll
                    for (int j = 0; j < 4; ++j) acc[i][j] = zz;
                for (int k0 = 0; k0 < 2 * DHz; k0 += 32) {
                    if (k0 < DHz) {
                        const float* src = rbuf + (long)(m0 + arow) * DHz + k0 + kp;
                        alignas(16) unsigned short tmp[16];
#pragma unroll
                        for (int it = 0; it < 4; ++it) {
                            float4 v = ((const float4*)src)[it];
                            tmp[it * 4 + 0] = f2bf(v.x); tmp[it * 4 + 1] = f2bf(v.y);
                            tmp[it * 4 + 2] = f2bf(v.z); tmp[it * 4 + 3] = f2bf(v.w);
                        }
                        *(int4*)(eA + arow * 40 + kp) = *(const int4*)tmp;
                        *(int4*)(eA + arow * 40 + kp + 8) = *(const int4*)(tmp + 8);
                    } else {
                        const unsigned short* src = Hbf
                            + ((long)(m0 + arow) * Tz + (Tz - 1)) * DHz + (k0 - DHz) + kp;
                        *(int4*)(eA + arow * 40 + kp) = *(const int4*)src;
                        *(int4*)(eA + arow * 40 + kp + 8) = *(const int4*)(src + 8);
                    }
                    {
                        const int4* wsrc = (const int4*)WpxP
                            + ((long)((k0 >> 5) * 6 + nt2)) * 512 + tid;
                        int4 v0 = wsrc[0];
                        int4 v1 = wsrc[256];
                        *(int4*)(eB + bd0) = v0;
                        *(int4*)(eB + bd1) = v1;
                    }
                    __syncthreads();
                    short8 af[4], bfr[4];
#pragma unroll
                    for (int i = 0; i < 4; ++i)
                        af[i] = *(const short8*)(eA + (wm * 64 + i * 16 + l15) * 40 + q * 8);
#pragma unroll
                    for (int j = 0; j < 4; ++j) {
                        int n = wn * 64 + j * 16 + l15;
                        bfr[j] = *(const short8*)(eB + n * 40 + ((q ^ ((n >> 3) & 3)) << 3));
                    }
#pragma unroll
                    for (int i = 0; i < 4; ++i)
#pragma unroll
                        for (int j = 0; j < 4; ++j)
                            acc[i][j] = __builtin_amdgcn_mfma_f32_16x16x32_bf16(af[i], bfr[j], acc[i][j], 0, 0, 0);
                    __syncthreads();
                }
#pragma unroll
                for (int i = 0; i < 4; ++i)
#pragma unroll
                    for (int j = 0; j < 4; ++j) {
                        int col = n0 + wn * 64 + j * 16 + l15;
#pragma unroll
                        for (int r = 0; r < 4; ++r) {
                            int row = m0 + wm * 64 + i * 16 + q * 4 + r;
                            __hip_atomic_store(&hst[(long)row * DHz + col],
                                               ftanh(acc[i][j][r]),
                                               __ATOMIC_RELAXED, __HIP_MEMORY_SCOPE_AGENT);
                        }
                    }
                asm volatile("s_waitcnt vmcnt(0)" ::: "memory");
                __syncthreads();
                if (tid == 0)
                    (void)__hip_atomic_fetch_add(ctr + 96, 1u, __ATOMIC_RELAXED,
                                                 __HIP_MEMORY_SCOPE_AGENT);
            } else {
                // ---- logits row b ----
                int b = task - 268;
                if (tid == 0)
                    while (__hip_atomic_load(ctr + 96, __ATOMIC_RELAXED,
                                             __HIP_MEMORY_SCOPE_AGENT) < 12u)
                        __builtin_amdgcn_s_sleep(8);
                __syncthreads();
                if (tid < 192) {
                    int ln = tid & 63, cc2 = tid >> 6;
                    float s2 = 0.f;
                    for (int k = ln; k < DHz; k += 64)
                        s2 += hst[(long)b * DHz + k] * W_lin[k * 3 + cc2];
#pragma unroll
                    for (int o = 32; o; o >>= 1) s2 += __shfl_xor(s2, o, 64);
                    if (ln == 0) out[b * 3 + cc2] = s2 + b_lin[cc2];
                }
            }
        }
    }
}

// ---------- fallback epilogue kernels ----------
__global__ __launch_bounds__(256) void k_scores(const unsigned short* __restrict__ Hbf,
                                                const unsigned short* __restrict__ WbP,
                                                const float* __restrict__ wv,
                                                float* __restrict__ scores) {
    __shared__ unsigned short sA[128 * 40];
    __shared__ unsigned short sB[128 * 40];
    __shared__ float sred[128];
    int tid = threadIdx.x;
    int n0 = blockIdx.x * 128;
    int m0 = blockIdx.y * 128;
    int wid = tid >> 6, lane = tid & 63, l15 = lane & 15, q = lane >> 4;
    int wm = wid >> 1, wn = wid & 1;
    int s0 = tid, s1 = tid + 256;
    int bd0 = (s0 >> 2) * 40 + (((s0 & 3) ^ (((s0 >> 2) >> 3) & 3)) << 3);
    int bd1 = (s1 >> 2) * 40 + (((s1 & 3) ^ (((s1 >> 2) >> 3) & 3)) << 3);
    f32x4 acc[4][4];
    f32x4 zz = {0.f, 0.f, 0.f, 0.f};
#pragma unroll
    for (int i = 0; i < 4; ++i)
#pragma unroll
        for (int j = 0; j < 4; ++j) acc[i][j] = zz;
    int arow = tid >> 1;
    int kp = (tid & 1) * 16;
    const unsigned short* asrc = Hbf + (long)(m0 + arow) * DHz;
    for (int k0 = 0; k0 < DHz; k0 += 32) {
        *(int4*)(sA + arow * 40 + kp) = *(const int4*)(asrc + k0 + kp);
        *(int4*)(sA + arow * 40 + kp + 8) = *(const int4*)(asrc + k0 + kp + 8);
        {
            const int4* wsrc = (const int4*)WbP + ((long)((k0 >> 5) * 6 + (n0 >> 7))) * 512 + tid;
            int4 v0 = wsrc[0];
            int4 v1 = wsrc[256];
            *(int4*)(sB + bd0) = v0;
            *(int4*)(sB + bd1) = v1;
        }
        __syncthreads();
        short8 af[4], bfr[4];
#pragma unroll
        for (int i = 0; i < 4; ++i)
            af[i] = *(const short8*)(sA + (wm * 64 + i * 16 + l15) * 40 + q * 8);
#pragma unroll
        for (int j = 0; j < 4; ++j) {
            int n = wn * 64 + j * 16 + l15;
            bfr[j] = *(const short8*)(sB + n * 40 + ((q ^ ((n >> 3) & 3)) << 3));
        }
#pragma unroll
        for (int i = 0; i < 4; ++i)
#pragma unroll
            for (int j = 0; j < 4; ++j)
                acc[i][j] = __builtin_amdgcn_mfma_f32_16x16x32_bf16(af[i], bfr[j], acc[i][j], 0, 0, 0);
        __syncthreads();
    }
    if (tid < 128) sred[tid] = 0.f;
    __syncthreads();
#pragma unroll
    for (int i = 0; i < 4; ++i)
#pragma unroll
        for (int r = 0; r < 4; ++r) {
            float sv = 0.f;
#pragma unroll
            for (int j = 0; j < 4; ++j) {
                int n = n0 + wn * 64 + j * 16 + l15;
                sv += ftanh(acc[i][j][r]) * wv[n];
            }
#pragma unroll
            for (int o = 1; o < 16; o <<= 1) sv += __shfl_xor(sv, o, 64);
            if (l15 == 0) atomicAdd(&sred[wm * 64 + i * 16 + q * 4 + r], sv);
        }
    __syncthreads();
    if (tid < 128) atomicAdd(&scores[m0 + tid], sred[tid]);
}

__global__ __launch_bounds__(128) void k_attn(const float* __restrict__ scores,
                                              const int* __restrict__ lens,
                                              const unsigned short* __restrict__ Hbf,
                                              float* __restrict__ rbuf) {
    int b = blockIdx.x, t = threadIdx.x;
    __shared__ float sal[Tz];
    __shared__ float rA[2], rB[2];
    int len = lens[b];
    float s = (t < len) ? scores[b * Tz + t] : -1e9f;
    float m = s;
#pragma unroll
    for (int o = 32; o; o >>= 1) m = fmaxf(m, __shfl_xor(m, o, 64));
    if ((t & 63) == 0) rA[t >> 6] = m;
    __syncthreads();
    m = fmaxf(rA[0], rA[1]);
    float e = expf(s - m);
    float sum = e;
#pragma unroll
    for (int o = 32; o; o >>= 1) sum += __shfl_xor(sum, o, 64);
    if ((t & 63) == 0) rB[t >> 6] = sum;
    __syncthreads();
    sum = rB[0] + rB[1];
    sal[t] = e / sum;
    __syncthreads();
    if (t < 96) {
        const unsigned short* hp = Hbf + (long)b * Tz * DHz + t * 8;
        float acc[8] = {};
        for (int tt = 0; tt < Tz; ++tt) {
            short8 v = *(const short8*)(hp + (long)tt * DHz);
            float a = sal[tt];
            const unsigned short* pv = (const unsigned short*)&v;
#pragma unroll
            for (int e2 = 0; e2 < 8; ++e2) acc[e2] += a * bf2f(pv[e2]);
        }
        float* rp = rbuf + (long)b * DHz + t * 8;
#pragma unroll
        for (int e2 = 0; e2 < 8; ++e2) rp[e2] = acc[e2];
    }
}

__global__ __launch_bounds__(256) void k_hstar(const float* __restrict__ rbuf,
                                               const unsigned short* __restrict__ Hbf,
                                               const unsigned short* __restrict__ WbP,
                                               float* __restrict__ hst) {
    __shared__ unsigned short sA[128 * 40];
    __shared__ unsigned short sB[128 * 40];
    int tid = threadIdx.x;
    int n0 = blockIdx.x * 128;
    int m0 = blockIdx.y * 128;
    int wid = tid >> 6, lane = tid & 63, l15 = lane & 15, q = lane >> 4;
    int wm = wid >> 1, wn = wid & 1;
    int arow = tid >> 1;
    int kp = (tid & 1) * 16;
    int s0 = tid, s1 = tid + 256;
    int bd0 = (s0 >> 2) * 40 + (((s0 & 3) ^ (((s0 >> 2) >> 3) & 3)) << 3);
    int bd1 = (s1 >> 2) * 40 + (((s1 & 3) ^ (((s1 >> 2) >> 3) & 3)) << 3);
    f32x4 acc[4][4];
    f32x4 zz = {0.f, 0.f, 0.f, 0.f};
#pragma unroll
    for (int i = 0; i < 4; ++i)
#pragma unroll
        for (int j = 0; j < 4; ++j) acc[i][j] = zz;
    for (int k0 = 0; k0 < 2 * DHz; k0 += 32) {
        if (k0 < DHz) {
            const float* src = rbuf + (long)(m0 + arow) * DHz + k0 + kp;
            alignas(16) unsigned short tmp[16];
#pragma unroll
            for (int it = 0; it < 4; ++it) {
                float4 v = ((const float4*)src)[it];
                tmp[it * 4 + 0] = f2bf(v.x); tmp[it * 4 + 1] = f2bf(v.y);
                tmp[it * 4 + 2] = f2bf(v.z); tmp[it * 4 + 3] = f2bf(v.w);
            }
            *(int4*)(sA + arow * 40 + kp) = *(const int4*)tmp;
            *(int4*)(sA + arow * 40 + kp + 8) = *(const int4*)(tmp + 8);
        } else {
            const unsigned short* src = Hbf + ((long)(m0 + arow) * Tz + (Tz - 1)) * DHz
                                      + (k0 - DHz) + kp;
            *(int4*)(sA + arow * 40 + kp) = *(const int4*)src;
            *(int4*)(sA + arow * 40 + kp + 8) = *(const int4*)(src + 8);
        }
        {
            const int4* wsrc = (const int4*)WbP + ((long)((k0 >> 5) * 6 + (n0 >> 7))) * 512 + tid;
            int4 v0 = wsrc[0];
            int4 v1 = wsrc[256];
            *(int4*)(sB + bd0) = v0;
            *(int4*)(sB + bd1) = v1;
        }
        __syncthreads();
        short8 af[4], bfr[4];
#pragma unroll
        for (int i = 0; i < 4; ++i)
            af[i] = *(const short8*)(sA + (wm * 64 + i * 16 + l15) * 40 + q * 8);
#pragma unroll
        for (int j = 0; j < 4; ++j) {
            int n = wn * 64 + j * 16 + l15;
            bfr[j] = *(const short8*)(sB + n * 40 + ((q ^ ((n >> 3) & 3)) << 3));
        }
#pragma unroll
        for (int i = 0; i < 4; ++i)
#pragma unroll
            for (int j = 0; j < 4; ++j)
                acc[i][j] = __builtin_amdgcn_mfma_f32_16x16x32_bf16(af[i], bfr[j], acc[i][j], 0, 0, 0);
        __syncthreads();
    }
#pragma unroll
    for (int i = 0; i < 4; ++i)
#pragma unroll
        for (int j = 0; j < 4; ++j) {
            int col = n0 + wn * 64 + j * 16 + l15;
#pragma unroll
            for (int r = 0; r < 4; ++r) {
                int row = m0 + wm * 64 + i * 16 + q * 4 + r;
                hst[(long)row * DHz + col] = ftanh(acc[i][j][r]);
            }
        }
}

__global__ void k_logits(const float* __restrict__ hst, const float* __restrict__ Wl,
                         const float* __restrict__ bl, float* __restrict__ out) {
    int b = blockIdx.x;
    int lane = threadIdx.x & 63, c = threadIdx.x >> 6;
    float s = 0.f;
    for (int k = lane; k < DHz; k += 64) s += hst[(long)b * DHz + k] * Wl[k * 3 + c];
#pragma unroll
    for (int o = 32; o; o >>= 1) s += __shfl_xor(s, o, 64);
    if (lane == 0) out[b * 3 + c] = s + bl[c];
}

extern "C" void kernel_launch(void* const* d_in, const int* in_sizes, int n_in,
                              void* d_out, int out_size, void* d_ws, size_t ws_size,
                              hipStream_t stream) {
    (void)in_sizes; (void)n_in; (void)out_size; (void)ws_size;
    const int*   sent   = (const int*)d_in[0];
    const int*   target = (const int*)d_in[1];
    const int*   lens   = (const int*)d_in[2];
    const float* emb    = (const float*)d_in[3];
    const float* temb   = (const float*)d_in[4];
    const float* W_ih   = (const float*)d_in[5];
    const float* W_hh   = (const float*)d_in[6];
    const float* b_lstm = (const float*)d_in[7];
    const float* Wh     = (const float*)d_in[8];
    const float* wv     = (const float*)d_in[10];
    const float* Wp     = (const float*)d_in[11];
    const float* Wx     = (const float*)d_in[12];
    const float* W_lin  = (const float*)d_in[13];
    const float* b_lin  = (const float*)d_in[14];
    float* out = (float*)d_out;

    char* ws = (char*)d_ws;
    size_t off = 0;
    auto alloc = [&](size_t bytes) -> void* {
        void* p = ws + off;
        off = (off + bytes + 255) & ~(size_t)255;
        return p;
    };
    unsigned short* xW    = (unsigned short*)alloc((size_t)32768 * G4z * 2);
    unsigned short* Hbf   = (unsigned short*)alloc((size_t)Bz * Tz * DHz * 2);
    unsigned short* WihbP = (unsigned short*)alloc((size_t)24 * 24 * 512 * 16);
    unsigned short* Wih2P = (unsigned short*)alloc((size_t)24 * 24 * 512 * 16);
    unsigned short* WhhP  = (unsigned short*)alloc((size_t)48 * 6144 * 16);
    unsigned short* WhbP  = (unsigned short*)alloc((size_t)24 * 6 * 512 * 16);
    unsigned short* WpxP  = (unsigned short*)alloc((size_t)48 * 6 * 512 * 16);
    float* constg = (float*)alloc((size_t)Bz * G4z * 4);
    float* cbuf   = (float*)alloc((size_t)Bz * DHz * 4);
    float* scores = (float*)alloc((size_t)Bz * Tz * 4);
    float* rbuf   = (float*)alloc((size_t)Bz * DHz * 4);
    float* hst    = (float*)alloc((size_t)Bz * DHz * 4);
    unsigned* bar = (unsigned*)alloc(65536);    // flags (49152B) + 4 ctr lines in tail
    unsigned* xwc = (unsigned*)alloc(16384);    // xW arrival counters: 128 x 128B

    k_prep_all<<<1584, 256, 0, stream>>>(W_ih, Wh, Wp, Wx, WihbP, Wih2P, WhbP, WpxP);
    k_prep_whh<<<1152, 256, 0, stream>>>(W_hh, WhhP);
    hipMemsetAsync(scores, 0, (size_t)Bz * Tz * 4, stream);
    hipMemsetAsync(bar, 0, 65536, stream);
    hipMemsetAsync(xwc, 0, 16384, stream);

    hipFuncSetAttribute((const void*)k_lstm_all,
                        hipFuncAttributeMaxDynamicSharedMemorySize, 98304);
    int t0v = 0, t1v = Tz, fusev = 1, nprodv = NGRID - NBLK;
    unsigned short* xWp = xW;
    float* cgp = constg;
    const unsigned short* whp = WhhP;
    unsigned short* hbp = Hbf;
    float* cbp = cbuf;
    const int* lnp = lens;
    unsigned* barp = bar;
    unsigned* xwcp = xwc;
    const float* embp = emb;
    const int* sentp = sent;
    const unsigned short* wihp = WihbP;
    const unsigned short* whbp = WhbP;
    const float* wvp = wv;
    float* scp = scores;
    const int* tgtp = target;
    const float* tembp = temb;
    const unsigned short* wih2p = Wih2P;
    const float* blp = b_lstm;
    float* rbp = rbuf;
    const unsigned short* wpxp = WpxP;
    float* hstp = hst;
    const float* wlp = W_lin;
    const float* blnp = b_lin;
    float* outp = out;
    void* kargs[] = {&t0v, &t1v, &xWp, &cgp, &whp, &hbp, &cbp, &lnp, &barp,
                     &xwcp, &fusev, &embp, &sentp, &wihp, &nprodv,
                     &whbp, &wvp, &scp, &tgtp, &tembp, &wih2p, &blp,
                     &rbp, &wpxp, &hstp, &wlp, &blnp, &outp};
    hipError_t ce = hipLaunchCooperativeKernel(reinterpret_cast<void*>(k_lstm_all),
                                               dim3(NGRID), dim3(256), kargs, 98304, stream);
    if (ce != hipSuccess) {
        // fallback: fully serial pipeline (kernel boundaries = coherence)
        k_gemm_cg<<<dim3(24, 2), 256, 0, stream>>>(target, temb, Wih2P, b_lstm, constg);
        k_gemm_x<<<dim3(24, 256), 256, 0, stream>>>(emb, sent, WihbP, xW);
        for (int t = 0; t < Tz; ++t)
            k_lstm_all<<<NBLK, 256, 98304, stream>>>(t, t + 1, xW, constg, WhhP, Hbf,
                                                     cbuf, lens, bar, xwc, 0,
                                                     emb, sent, WihbP, 0,
                                                     WhbP, wv, scores,
                                                     target, temb, Wih2P, b_lstm,
                                                     rbuf, WpxP, hst, W_lin, b_lin, out);
        k_scores<<<dim3(6, 256), 256, 0, stream>>>(Hbf, WhbP, wv, scores);
        k_attn<<<Bz, 128, 0, stream>>>(scores, lens, Hbf, rbuf);
        k_hstar<<<dim3(6, 2), 256, 0, stream>>>(rbuf, Hbf, WpxP, hst);
        k_logits<<<Bz, 192, 0, stream>>>(hst, W_lin, b_lin, out);
    }
}